// Round 1
// baseline (2146.966 us; speedup 1.0000x reference)
//
#include <hip/hip_runtime.h>

// BandSplit fused kernel (fp32, correctness-first round).
// out[b,c,t,f] = (1/ola[f]) * sum_{k,w: idx[k,w]==f} mask[k,w] *
//                ( post_b[k, 2w+c] + sum_d z[b,t,k,d] * post_w[k,d,2w+c] )
// z[b,t,k,d]   = pre_b[k,d] + sum_i g[b,t,k,i] * pre_w[k,i,d]
// g[b,t,k,2w+c]= x[b,c,t,idx[k,w]] * mel[k,w]*mask[k,w]

#define TPB 256
constexpr int D_OUTC = 128;   // D
constexpr int T_LEN  = 512;
constexpr int C_INC  = 2;
constexpr int F_BINS = 1025;
constexpr int N_BANDS= 128;
constexpr int MT     = 32;    // (b,t) rows per block
constexpr int MAX_W  = 80;
constexpr int MAX_I1 = 2 * MAX_W;           // 160
constexpr int MAX_I1P= (MAX_I1 + 31) & ~31; // 160
constexpr int GSTR   = 36;    // padded col-stride for gT/zT: 16B-aligned, rotates banks

__global__ __launch_bounds__(TPB, 2)
void bandsplit_fused(const float* __restrict__ x,
                     const float* __restrict__ pre_w,
                     const float* __restrict__ pre_b,
                     const float* __restrict__ post_w,
                     const float* __restrict__ post_b,
                     const float* __restrict__ mel,
                     const float* __restrict__ mask,
                     const float* __restrict__ ola,
                     const int*   __restrict__ idx,
                     float* __restrict__ out,
                     int W)
{
    const int i1  = 2 * W;
    const int I1P = (i1 + 31) & ~31;
    const int k     = blockIdx.y;
    const int mbase = blockIdx.x * MT;
    const int b     = mbase / T_LEN;     // MT divides T_LEN -> whole block same b
    const int t0    = mbase % T_LEN;
    const int tid = threadIdx.x;
    const int td  = tid & 31;            // d/o tile group (4 cols each)
    const int tm  = tid >> 5;            // m tile group (4 rows each), 0..7

    __shared__ float gT[MAX_I1P * GSTR]; // gT[i*GSTR + m]
    __shared__ float zT[D_OUTC * GSTR];  // zT[d*GSTR + m]
    __shared__ float wS[32 * D_OUTC];    // 32-row weight chunk
    __shared__ float s_preb[D_OUTC];
    __shared__ float s_postb[MAX_I1];
    __shared__ float s_melmask[MAX_W];
    __shared__ float s_mask[MAX_W];
    __shared__ float s_iola[MAX_W];
    __shared__ int   s_idx[MAX_W];

    // ---- stage band tables ----
    for (int j = tid; j < W; j += TPB) {
        int   f  = idx[k * W + j];
        float mv = mel[k * W + j];
        float mk = mask[k * W + j];
        s_idx[j]     = f;
        s_melmask[j] = mv * mk;
        s_mask[j]    = mk;
        s_iola[j]    = 1.0f / ola[f];
    }
    for (int j = tid; j < D_OUTC; j += TPB) s_preb[j]  = pre_b[k * D_OUTC + j];
    for (int j = tid; j < i1;     j += TPB) s_postb[j] = post_b[k * i1 + j];
    for (int j = tid; j < I1P * GSTR; j += TPB) gT[j] = 0.f;  // incl. K-padding rows
    __syncthreads();

    // ---- gather: gT[(2w+c)][m] = x[b,c,t0+m, idx[w]] * mel*mask ----
    // w fastest across threads: idx[w] is (mostly) a contiguous bin run -> coalesced
    for (int j = tid; j < MT * i1; j += TPB) {
        int w  = j % W;
        int cm = j / W;
        int c  = cm & 1;
        int ml = cm >> 1;
        int f  = s_idx[w];
        float v = x[((b * C_INC + c) * T_LEN + (t0 + ml)) * F_BINS + f] * s_melmask[w];
        gT[(2 * w + c) * GSTR + ml] = v;
    }
    __syncthreads();

    // ---- GEMM1: z[m][d] = sum_i g[m][i] * pre_w[k][i][d] ----
    float az[4][4] = {};   // [r(m)][j(d)]
    for (int i0 = 0; i0 < I1P; i0 += 32) {
        for (int j = tid; j < 32 * D_OUTC; j += TPB) {
            int ii = j >> 7, d = j & 127;
            int i  = i0 + ii;
            wS[j] = (i < i1) ? pre_w[(k * i1 + i) * D_OUTC + d] : 0.f;
        }
        __syncthreads();
        #pragma unroll 8
        for (int ii = 0; ii < 32; ++ii) {
            const float4 wv = *reinterpret_cast<const float4*>(&wS[ii * D_OUTC + td * 4]);
            const float4 gv = *reinterpret_cast<const float4*>(&gT[(i0 + ii) * GSTR + tm * 4]);
            az[0][0] += gv.x * wv.x; az[0][1] += gv.x * wv.y; az[0][2] += gv.x * wv.z; az[0][3] += gv.x * wv.w;
            az[1][0] += gv.y * wv.x; az[1][1] += gv.y * wv.y; az[1][2] += gv.y * wv.z; az[1][3] += gv.y * wv.w;
            az[2][0] += gv.z * wv.x; az[2][1] += gv.z * wv.y; az[2][2] += gv.z * wv.z; az[2][3] += gv.z * wv.w;
            az[3][0] += gv.w * wv.x; az[3][1] += gv.w * wv.y; az[3][2] += gv.w * wv.z; az[3][3] += gv.w * wv.w;
        }
        __syncthreads();
    }
    // write z (+bias) transposed
    #pragma unroll
    for (int jj = 0; jj < 4; ++jj) {
        int d = td * 4 + jj;
        float bb = s_preb[d];
        #pragma unroll
        for (int r = 0; r < 4; ++r)
            zT[d * GSTR + tm * 4 + r] = az[r][jj] + bb;
    }
    __syncthreads();

    // ---- GEMM2 + epilogue + scatter ----
    const int NOG = (i1 + 127) >> 7;
    for (int og = 0; og < NOG; ++og) {
        float ay[4][4] = {};   // [r(m)][j(o)]
        for (int d0 = 0; d0 < D_OUTC; d0 += 32) {
            for (int j = tid; j < 32 * D_OUTC; j += TPB) {
                int dd = j >> 7, oo = j & 127;
                int o  = og * 128 + oo;
                wS[j] = (o < i1) ? post_w[(k * D_OUTC + d0 + dd) * i1 + o] : 0.f;
            }
            __syncthreads();
            #pragma unroll 8
            for (int dd = 0; dd < 32; ++dd) {
                const float4 wv = *reinterpret_cast<const float4*>(&wS[dd * D_OUTC + td * 4]);
                const float4 zv = *reinterpret_cast<const float4*>(&zT[(d0 + dd) * GSTR + tm * 4]);
                ay[0][0] += zv.x * wv.x; ay[0][1] += zv.x * wv.y; ay[0][2] += zv.x * wv.z; ay[0][3] += zv.x * wv.w;
                ay[1][0] += zv.y * wv.x; ay[1][1] += zv.y * wv.y; ay[1][2] += zv.y * wv.z; ay[1][3] += zv.y * wv.w;
                ay[2][0] += zv.z * wv.x; ay[2][1] += zv.z * wv.y; ay[2][2] += zv.z * wv.z; ay[2][3] += zv.z * wv.w;
                ay[3][0] += zv.w * wv.x; ay[3][1] += zv.w * wv.y; ay[3][2] += zv.w * wv.z; ay[3][3] += zv.w * wv.w;
            }
            __syncthreads();
        }
        #pragma unroll
        for (int jj = 0; jj < 4; ++jj) {
            int o = og * 128 + td * 4 + jj;
            if (o < i1) {
                int w = o >> 1, c = o & 1;
                float mk = s_mask[w];
                if (mk != 0.f) {
                    int f = s_idx[w];
                    float scale = mk * s_iola[w];
                    float bb = s_postb[o];
                    #pragma unroll
                    for (int r = 0; r < 4; ++r) {
                        int ml = tm * 4 + r;
                        float val = (ay[r][jj] + bb) * scale;
                        atomicAdd(&out[((b * C_INC + c) * T_LEN + (t0 + ml)) * F_BINS + f], val);
                    }
                }
            }
        }
    }
}

// Safety-net kernel for unexpected W (> MAX_W): one (m,k) per block, 128 threads.
__global__ void bandsplit_naive(const float* __restrict__ x,
                                const float* __restrict__ pre_w,
                                const float* __restrict__ pre_b,
                                const float* __restrict__ post_w,
                                const float* __restrict__ post_b,
                                const float* __restrict__ mel,
                                const float* __restrict__ mask,
                                const float* __restrict__ ola,
                                const int*   __restrict__ idx,
                                float* __restrict__ out,
                                int W)
{
    const int i1 = 2 * W;
    extern __shared__ float sh[];
    float* g = sh;          // i1
    float* z = sh + i1;     // 128
    const int m = blockIdx.x, k = blockIdx.y;
    const int b = m / T_LEN, t = m % T_LEN;
    const int tid = threadIdx.x;
    for (int j = tid; j < i1; j += 128) {
        int w = j >> 1, c = j & 1;
        int f = idx[k * W + w];
        g[j] = x[((b * C_INC + c) * T_LEN + t) * F_BINS + f] * mel[k * W + w] * mask[k * W + w];
    }
    __syncthreads();
    {
        int d = tid;
        float a = pre_b[k * D_OUTC + d];
        for (int i = 0; i < i1; ++i) a += g[i] * pre_w[(k * i1 + i) * D_OUTC + d];
        z[d] = a;
    }
    __syncthreads();
    for (int o = tid; o < i1; o += 128) {
        int w = o >> 1, c = o & 1;
        float mk = mask[k * W + w];
        if (mk == 0.f) continue;
        float a = post_b[k * i1 + o];
        for (int d = 0; d < D_OUTC; ++d) a += z[d] * post_w[(k * D_OUTC + d) * i1 + o];
        int f = idx[k * W + w];
        atomicAdd(&out[((b * C_INC + c) * T_LEN + t) * F_BINS + f], a * mk / ola[f]);
    }
}

extern "C" void kernel_launch(void* const* d_in, const int* in_sizes, int n_in,
                              void* d_out, int out_size, void* d_ws, size_t ws_size,
                              hipStream_t stream) {
    const float* x      = (const float*)d_in[0];
    const float* pre_w  = (const float*)d_in[1];
    const float* pre_b  = (const float*)d_in[2];
    const float* post_w = (const float*)d_in[3];
    const float* post_b = (const float*)d_in[4];
    const float* mel    = (const float*)d_in[5];
    const float* mask   = (const float*)d_in[6];
    const float* ola    = (const float*)d_in[7];
    const int*   idxp   = (const int*)d_in[8];
    float* out = (float*)d_out;

    const int W = in_sizes[8] / N_BANDS;
    const int Mrows = (in_sizes[0] / (C_INC * F_BINS));   // B*T = 4096

    // atomics accumulate into out -> must zero every call (harness doesn't re-poison)
    hipMemsetAsync(d_out, 0, (size_t)out_size * sizeof(float), stream);

    if (W <= MAX_W) {
        dim3 grid(Mrows / MT, N_BANDS);
        bandsplit_fused<<<grid, TPB, 0, stream>>>(x, pre_w, pre_b, post_w, post_b,
                                                  mel, mask, ola, idxp, out, W);
    } else {
        dim3 grid(Mrows, N_BANDS);
        size_t shmem = (size_t)(2 * W + D_OUTC) * sizeof(float);
        bandsplit_naive<<<grid, 128, shmem, stream>>>(x, pre_w, pre_b, post_w, post_b,
                                                      mel, mask, ola, idxp, out, W);
    }
}

// Round 2
// 299.922 us; speedup vs baseline: 7.1584x; 7.1584x over previous
//
#include <hip/hip_runtime.h>

typedef __attribute__((ext_vector_type(8))) short short8;
typedef __attribute__((ext_vector_type(4))) float f32x4;

#define TPB 256
constexpr int D_OUTC = 128;   // D
constexpr int T_LEN  = 512;
constexpr int C_INC  = 2;
constexpr int F_BINS = 1025;
constexpr int N_BANDS= 128;
constexpr int MAX_W  = 80;
constexpr int MAX_K1P= 160;            // roundup32(2*MAX_W)
constexpr int STR1_MAX = MAX_K1P + 8;  // 168 bf16 -> 336B row stride (16B aligned, bank-rotating)
constexpr int ZSTR   = 136;            // 128+8 -> 272B row stride

__device__ inline unsigned short f2bf(float f) {
  unsigned int u = __float_as_uint(f);
  unsigned int r = u + 0x7FFFu + ((u >> 16) & 1u);   // RNE
  return (unsigned short)(r >> 16);
}
__device__ inline float bf2f(unsigned short h) {
  return __uint_as_float(((unsigned int)h) << 16);
}

// ---------------- weight prep: split + transpose to MFMA B-fragment layout ----------------
// wB1[band][d][kk] = pre_w[band][kk][d]   (kk in [0,K1P), zero-padded)
__global__ void prep_w1(const float* __restrict__ pre_w,
                        unsigned short* __restrict__ hh, unsigned short* __restrict__ ll,
                        int i1, int K1P) {
  int e = blockIdx.x * 256 + threadIdx.x;
  int total = N_BANDS * 128 * K1P;
  if (e >= total) return;
  int kk = e % K1P;
  int rem = e / K1P;
  int d = rem & 127;
  int band = rem >> 7;
  float v = (kk < i1) ? pre_w[((size_t)band * i1 + kk) * 128 + d] : 0.f;
  unsigned short h = f2bf(v);
  hh[e] = h;
  ll[e] = f2bf(v - bf2f(h));
}
// wB2[band][o][dd] = post_w[band][dd][o]  (o in [0,OSTR), zero-padded)
__global__ void prep_w2(const float* __restrict__ post_w,
                        unsigned short* __restrict__ hh, unsigned short* __restrict__ ll,
                        int i1, int OSTR) {
  int e = blockIdx.x * 256 + threadIdx.x;
  int total = N_BANDS * OSTR * 128;
  if (e >= total) return;
  int dd = e & 127;
  int rem = e >> 7;
  int o = rem % OSTR;
  int band = rem / OSTR;
  float v = (o < i1) ? post_w[((size_t)band * 128 + dd) * i1 + o] : 0.f;
  unsigned short h = f2bf(v);
  hh[e] = h;
  ll[e] = f2bf(v - bf2f(h));
}

// ---------------- fused MFMA kernel: one (band, 64-row) tile per block ----------------
__global__ __launch_bounds__(TPB, 3)
void bandsplit_mfma(const float* __restrict__ x,
                    const unsigned short* __restrict__ wB1h,
                    const unsigned short* __restrict__ wB1l,
                    const unsigned short* __restrict__ wB2h,
                    const unsigned short* __restrict__ wB2l,
                    const float* __restrict__ pre_b,
                    const float* __restrict__ post_b,
                    const float* __restrict__ mel,
                    const float* __restrict__ mask,
                    const float* __restrict__ ola,
                    const int* __restrict__ idx,
                    float* __restrict__ out,
                    int W, int i1, int K1P)
{
  const int k     = blockIdx.y;
  const int mbase = blockIdx.x * 64;
  const int b     = mbase >> 9;        // /T_LEN (64 | 512)
  const int t0    = mbase & 511;
  const int tid   = threadIdx.x;
  const int lane  = tid & 63;
  const int wid   = tid >> 6;          // 4 waves, each owns 16 rows
  const int lr    = lane & 15;
  const int lk    = lane >> 4;
  const int STR1  = K1P + 8;

  __shared__ unsigned short smem[64 * STR1_MAX * 2];  // gA(hi|lo); aliased by zA(hi|lo)
  unsigned short* gAh = smem;
  unsigned short* gAl = smem + 64 * STR1;
  unsigned short* zAh = smem;
  unsigned short* zAl = smem + 64 * ZSTR;
  __shared__ float s_melmask[MAX_W], s_mask_s[MAX_W], s_iola[MAX_W];
  __shared__ int   s_idx[MAX_W];
  __shared__ float s_preb[128];
  __shared__ float s_postb[2 * MAX_W];

  // ---- stage per-band tables ----
  for (int j = tid; j < W; j += TPB) {
    int   f  = idx[k * W + j];
    float mv = mel[k * W + j];
    float mk = mask[k * W + j];
    s_idx[j]     = f;
    s_melmask[j] = mv * mk;
    s_mask_s[j]  = mk;
    s_iola[j]    = 1.0f / ola[f];
  }
  for (int j = tid; j < 128; j += TPB) s_preb[j]  = pre_b[k * 128 + j];
  for (int j = tid; j < i1;  j += TPB) s_postb[j] = post_b[k * i1 + j];
  __syncthreads();

  // effective band width (mask is a 1s-prefix): skip the zero-padded tail entirely
  int len = 0;
  for (int w = 0; w < W; ++w) len += (s_mask_s[w] != 0.f) ? 1 : 0;
  const int i1e  = 2 * len;
  const int k1p  = (i1e + 31) & ~31;
  const int nks1 = k1p >> 5;
  const int nOT  = (i1e + 15) >> 4;

  // ---- gather: gA[m][i] = x[b, i&1, t0+m, idx[i>>1]] * mel*mask, split hi/lo bf16 ----
  {
    int m = tid / k1p;
    int i = tid - m * k1p;
    while (m < 64) {
      int w = i >> 1, c = i & 1;
      float v = 0.f;
      if (w < W) {
        float mm = s_melmask[w];
        if (mm != 0.f)
          v = x[((b * C_INC + c) * T_LEN + t0 + m) * F_BINS + s_idx[w]] * mm;
      }
      unsigned short h = f2bf(v);
      gAh[m * STR1 + i] = h;
      gAl[m * STR1 + i] = f2bf(v - bf2f(h));
      i += TPB;
      while (i >= k1p) { i -= k1p; ++m; }
    }
  }
  __syncthreads();

  // ---- GEMM1: z[m][d] = g[m][:] . pre_w[k][:][d]  (bf16x3 emulation, fp32 accum) ----
  f32x4 acc1[8] = {};
  const int m0 = wid * 16;
  for (int ks = 0; ks < nks1; ++ks) {
    const short8 ah = *(const short8*)&gAh[(m0 + lr) * STR1 + ks * 32 + lk * 8];
    const short8 al = *(const short8*)&gAl[(m0 + lr) * STR1 + ks * 32 + lk * 8];
    #pragma unroll
    for (int dt = 0; dt < 8; ++dt) {
      const int off = (k * 128 + dt * 16 + lr) * K1P + ks * 32 + lk * 8;
      const short8 bh = *(const short8*)&wB1h[off];
      const short8 bl = *(const short8*)&wB1l[off];
      acc1[dt] = __builtin_amdgcn_mfma_f32_16x16x32_bf16(ah, bh, acc1[dt], 0, 0, 0);
      acc1[dt] = __builtin_amdgcn_mfma_f32_16x16x32_bf16(al, bh, acc1[dt], 0, 0, 0);
      acc1[dt] = __builtin_amdgcn_mfma_f32_16x16x32_bf16(ah, bl, acc1[dt], 0, 0, 0);
    }
  }
  __syncthreads();   // all gA reads done before zA overwrites the same LDS

  // ---- z + bias, split hi/lo into LDS (A-layout for GEMM2) ----
  #pragma unroll
  for (int dt = 0; dt < 8; ++dt) {
    const int d = dt * 16 + lr;                 // C layout: col = lane&15
    #pragma unroll
    for (int r = 0; r < 4; ++r) {
      const int m = m0 + lk * 4 + r;            // C layout: row = 4*(lane>>4)+reg
      float z = acc1[dt][r] + s_preb[d];
      unsigned short h = f2bf(z);
      zAh[m * ZSTR + d] = h;
      zAl[m * ZSTR + d] = f2bf(z - bf2f(h));
    }
  }
  __syncthreads();

  // ---- GEMM2: y[m][o] = z[m][:] . post_w[k][:][o], only live o-tiles ----
  f32x4 acc2[10] = {};
  for (int ks = 0; ks < 4; ++ks) {
    const short8 ah = *(const short8*)&zAh[(m0 + lr) * ZSTR + ks * 32 + lk * 8];
    const short8 al = *(const short8*)&zAl[(m0 + lr) * ZSTR + ks * 32 + lk * 8];
    #pragma unroll
    for (int ot = 0; ot < 10; ++ot) {
      if (ot < nOT) {
        const int off = (k * K1P + ot * 16 + lr) * 128 + ks * 32 + lk * 8;
        const short8 bh = *(const short8*)&wB2h[off];
        const short8 bl = *(const short8*)&wB2l[off];
        acc2[ot] = __builtin_amdgcn_mfma_f32_16x16x32_bf16(ah, bh, acc2[ot], 0, 0, 0);
        acc2[ot] = __builtin_amdgcn_mfma_f32_16x16x32_bf16(al, bh, acc2[ot], 0, 0, 0);
        acc2[ot] = __builtin_amdgcn_mfma_f32_16x16x32_bf16(ah, bl, acc2[ot], 0, 0, 0);
      }
    }
  }

  // ---- epilogue: +bias, *1/ola, masked scatter-add (mask==1 on the i1e prefix) ----
  #pragma unroll
  for (int ot = 0; ot < 10; ++ot) {
    if (ot < nOT) {
      const int o = ot * 16 + lr;
      if (o < i1e) {
        const int w = o >> 1, c = o & 1;
        const float sc = s_iola[w];
        const float bb = s_postb[o];
        const int   f  = s_idx[w];
        #pragma unroll
        for (int r = 0; r < 4; ++r) {
          const int m = m0 + lk * 4 + r;
          atomicAdd(&out[((b * C_INC + c) * T_LEN + t0 + m) * F_BINS + f],
                    (acc2[ot][r] + bb) * sc);
        }
      }
    }
  }
}

// ================= fallback: round-1 fp32 fused kernel (known good) =================
constexpr int MT     = 32;
constexpr int MAX_I1 = 2 * MAX_W;
constexpr int MAX_I1P= (MAX_I1 + 31) & ~31;
constexpr int GSTR   = 36;

__global__ __launch_bounds__(TPB, 2)
void bandsplit_fused(const float* __restrict__ x,
                     const float* __restrict__ pre_w,
                     const float* __restrict__ pre_b,
                     const float* __restrict__ post_w,
                     const float* __restrict__ post_b,
                     const float* __restrict__ mel,
                     const float* __restrict__ mask,
                     const float* __restrict__ ola,
                     const int*   __restrict__ idx,
                     float* __restrict__ out,
                     int W)
{
    const int i1  = 2 * W;
    const int I1P = (i1 + 31) & ~31;
    const int k     = blockIdx.y;
    const int mbase = blockIdx.x * MT;
    const int b     = mbase / T_LEN;
    const int t0    = mbase % T_LEN;
    const int tid = threadIdx.x;
    const int td  = tid & 31;
    const int tm  = tid >> 5;

    __shared__ float gT[MAX_I1P * GSTR];
    __shared__ float zT[D_OUTC * GSTR];
    __shared__ float wS[32 * D_OUTC];
    __shared__ float s_preb[D_OUTC];
    __shared__ float s_postb[MAX_I1];
    __shared__ float s_melmask[MAX_W];
    __shared__ float s_mask[MAX_W];
    __shared__ float s_iola[MAX_W];
    __shared__ int   s_idx[MAX_W];

    for (int j = tid; j < W; j += TPB) {
        int   f  = idx[k * W + j];
        float mv = mel[k * W + j];
        float mk = mask[k * W + j];
        s_idx[j]     = f;
        s_melmask[j] = mv * mk;
        s_mask[j]    = mk;
        s_iola[j]    = 1.0f / ola[f];
    }
    for (int j = tid; j < D_OUTC; j += TPB) s_preb[j]  = pre_b[k * D_OUTC + j];
    for (int j = tid; j < i1;     j += TPB) s_postb[j] = post_b[k * i1 + j];
    for (int j = tid; j < I1P * GSTR; j += TPB) gT[j] = 0.f;
    __syncthreads();

    for (int j = tid; j < MT * i1; j += TPB) {
        int w  = j % W;
        int cm = j / W;
        int c  = cm & 1;
        int ml = cm >> 1;
        int f  = s_idx[w];
        float v = x[((b * C_INC + c) * T_LEN + (t0 + ml)) * F_BINS + f] * s_melmask[w];
        gT[(2 * w + c) * GSTR + ml] = v;
    }
    __syncthreads();

    float az[4][4] = {};
    for (int i0 = 0; i0 < I1P; i0 += 32) {
        for (int j = tid; j < 32 * D_OUTC; j += TPB) {
            int ii = j >> 7, d = j & 127;
            int i  = i0 + ii;
            wS[j] = (i < i1) ? pre_w[(k * i1 + i) * D_OUTC + d] : 0.f;
        }
        __syncthreads();
        #pragma unroll 8
        for (int ii = 0; ii < 32; ++ii) {
            const float4 wv = *reinterpret_cast<const float4*>(&wS[ii * D_OUTC + td * 4]);
            const float4 gv = *reinterpret_cast<const float4*>(&gT[(i0 + ii) * GSTR + tm * 4]);
            az[0][0] += gv.x * wv.x; az[0][1] += gv.x * wv.y; az[0][2] += gv.x * wv.z; az[0][3] += gv.x * wv.w;
            az[1][0] += gv.y * wv.x; az[1][1] += gv.y * wv.y; az[1][2] += gv.y * wv.z; az[1][3] += gv.y * wv.w;
            az[2][0] += gv.z * wv.x; az[2][1] += gv.z * wv.y; az[2][2] += gv.z * wv.z; az[2][3] += gv.z * wv.w;
            az[3][0] += gv.w * wv.x; az[3][1] += gv.w * wv.y; az[3][2] += gv.w * wv.z; az[3][3] += gv.w * wv.w;
        }
        __syncthreads();
    }
    #pragma unroll
    for (int jj = 0; jj < 4; ++jj) {
        int d = td * 4 + jj;
        float bb = s_preb[d];
        #pragma unroll
        for (int r = 0; r < 4; ++r)
            zT[d * GSTR + tm * 4 + r] = az[r][jj] + bb;
    }
    __syncthreads();

    const int NOG = (i1 + 127) >> 7;
    for (int og = 0; og < NOG; ++og) {
        float ay[4][4] = {};
        for (int d0 = 0; d0 < D_OUTC; d0 += 32) {
            for (int j = tid; j < 32 * D_OUTC; j += TPB) {
                int dd = j >> 7, oo = j & 127;
                int o  = og * 128 + oo;
                wS[j] = (o < i1) ? post_w[(k * D_OUTC + d0 + dd) * i1 + o] : 0.f;
            }
            __syncthreads();
            #pragma unroll 8
            for (int dd = 0; dd < 32; ++dd) {
                const float4 wv = *reinterpret_cast<const float4*>(&wS[dd * D_OUTC + td * 4]);
                const float4 zv = *reinterpret_cast<const float4*>(&zT[(d0 + dd) * GSTR + tm * 4]);
                ay[0][0] += zv.x * wv.x; ay[0][1] += zv.x * wv.y; ay[0][2] += zv.x * wv.z; ay[0][3] += zv.x * wv.w;
                ay[1][0] += zv.y * wv.x; ay[1][1] += zv.y * wv.y; ay[1][2] += zv.y * wv.z; ay[1][3] += zv.y * wv.w;
                ay[2][0] += zv.z * wv.x; ay[2][1] += zv.z * wv.y; ay[2][2] += zv.z * wv.z; ay[2][3] += zv.z * wv.w;
                ay[3][0] += zv.w * wv.x; ay[3][1] += zv.w * wv.y; ay[3][2] += zv.w * wv.z; ay[3][3] += zv.w * wv.w;
            }
            __syncthreads();
        }
        #pragma unroll
        for (int jj = 0; jj < 4; ++jj) {
            int o = og * 128 + td * 4 + jj;
            if (o < i1) {
                int w = o >> 1, c = o & 1;
                float mk = s_mask[w];
                if (mk != 0.f) {
                    int f = s_idx[w];
                    float scale = mk * s_iola[w];
                    float bb = s_postb[o];
                    #pragma unroll
                    for (int r = 0; r < 4; ++r) {
                        int ml = tm * 4 + r;
                        float val = (ay[r][jj] + bb) * scale;
                        atomicAdd(&out[((b * C_INC + c) * T_LEN + (t0 + ml)) * F_BINS + f], val);
                    }
                }
            }
        }
    }
}

__global__ void bandsplit_naive(const float* __restrict__ x,
                                const float* __restrict__ pre_w,
                                const float* __restrict__ pre_b,
                                const float* __restrict__ post_w,
                                const float* __restrict__ post_b,
                                const float* __restrict__ mel,
                                const float* __restrict__ mask,
                                const float* __restrict__ ola,
                                const int*   __restrict__ idx,
                                float* __restrict__ out,
                                int W)
{
    const int i1 = 2 * W;
    extern __shared__ float sh[];
    float* g = sh;
    float* z = sh + i1;
    const int m = blockIdx.x, k = blockIdx.y;
    const int b = m / T_LEN, t = m % T_LEN;
    const int tid = threadIdx.x;
    for (int j = tid; j < i1; j += 128) {
        int w = j >> 1, c = j & 1;
        int f = idx[k * W + w];
        g[j] = x[((b * C_INC + c) * T_LEN + t) * F_BINS + f] * mel[k * W + w] * mask[k * W + w];
    }
    __syncthreads();
    {
        int d = tid;
        float a = pre_b[k * D_OUTC + d];
        for (int i = 0; i < i1; ++i) a += g[i] * pre_w[(k * i1 + i) * D_OUTC + d];
        z[d] = a;
    }
    __syncthreads();
    for (int o = tid; o < i1; o += 128) {
        int w = o >> 1, c = o & 1;
        float mk = mask[k * W + w];
        if (mk == 0.f) continue;
        float a = post_b[k * i1 + o];
        for (int d = 0; d < D_OUTC; ++d) a += z[d] * post_w[(k * D_OUTC + d) * i1 + o];
        int f = idx[k * W + w];
        atomicAdd(&out[((b * C_INC + c) * T_LEN + t) * F_BINS + f], a * mk / ola[f]);
    }
}

extern "C" void kernel_launch(void* const* d_in, const int* in_sizes, int n_in,
                              void* d_out, int out_size, void* d_ws, size_t ws_size,
                              hipStream_t stream) {
    const float* x      = (const float*)d_in[0];
    const float* pre_w  = (const float*)d_in[1];
    const float* pre_b  = (const float*)d_in[2];
    const float* post_w = (const float*)d_in[3];
    const float* post_b = (const float*)d_in[4];
    const float* mel    = (const float*)d_in[5];
    const float* mask   = (const float*)d_in[6];
    const float* ola    = (const float*)d_in[7];
    const int*   idxp   = (const int*)d_in[8];
    float* out = (float*)d_out;

    const int W  = in_sizes[8] / N_BANDS;
    const int i1 = 2 * W;
    const int Mrows = in_sizes[0] / (C_INC * F_BINS);   // B*T = 4096

    // atomics accumulate into out -> zero every call
    hipMemsetAsync(d_out, 0, (size_t)out_size * sizeof(float), stream);

    const int K1P = (i1 + 31) & ~31;
    const size_t S1 = (size_t)N_BANDS * 128 * K1P;      // elems per split-weight array
    const size_t need = S1 * 4 * sizeof(unsigned short);

    if (W <= MAX_W && (Mrows % 64) == 0 && ws_size >= need) {
        unsigned short* wB1h = (unsigned short*)d_ws;
        unsigned short* wB1l = wB1h + S1;
        unsigned short* wB2h = wB1l + S1;
        unsigned short* wB2l = wB2h + S1;
        const int nb = (int)((S1 + 255) / 256);
        prep_w1<<<nb, 256, 0, stream>>>(pre_w,  wB1h, wB1l, i1, K1P);
        prep_w2<<<nb, 256, 0, stream>>>(post_w, wB2h, wB2l, i1, K1P);
        dim3 grid(Mrows / 64, N_BANDS);
        bandsplit_mfma<<<grid, TPB, 0, stream>>>(x, wB1h, wB1l, wB2h, wB2l,
                                                 pre_b, post_b, mel, mask, ola, idxp,
                                                 out, W, i1, K1P);
    } else if (W <= MAX_W) {
        dim3 grid(Mrows / MT, N_BANDS);
        bandsplit_fused<<<grid, TPB, 0, stream>>>(x, pre_w, pre_b, post_w, post_b,
                                                  mel, mask, ola, idxp, out, W);
    } else {
        dim3 grid(Mrows, N_BANDS);
        size_t shmem = (size_t)(2 * W + D_OUTC) * sizeof(float);
        bandsplit_naive<<<grid, 128, shmem, stream>>>(x, pre_w, pre_b, post_w, post_b,
                                                      mel, mask, ola, idxp, out, W);
    }
}

// Round 3
// 224.823 us; speedup vs baseline: 9.5496x; 1.3340x over previous
//
#include <hip/hip_runtime.h>
#include <hip/hip_fp16.h>

typedef __attribute__((ext_vector_type(8))) short short8;
typedef __attribute__((ext_vector_type(4))) float f32x4;

#define TPB 256
constexpr int D_OUTC = 128;   // D
constexpr int T_LEN  = 512;
constexpr int C_INC  = 2;
constexpr int F_BINS = 1025;
constexpr int N_BANDS= 128;
constexpr int MAX_W  = 80;
constexpr int STR1M  = 168;   // gA row stride (ushorts): 160 max + 8 pad
constexpr int ZSTRM  = 136;   // zA row stride: 128 + 8 pad
constexpr int SCAP   = 4224;  // y row capacity (sum 2*len <= 4100 by <=2-band overlap)

__device__ inline unsigned short f2bf(float f) {
  unsigned int u = __float_as_uint(f);
  unsigned int r = u + 0x7FFFu + ((u >> 16) & 1u);   // RNE
  return (unsigned short)(r >> 16);
}
__device__ inline float bf2f(unsigned short h) {
  return __uint_as_float(((unsigned int)h) << 16);
}

// ============ meta: len/lenP/off per band (single block, 128 threads) ============
__global__ void k_meta(const float* __restrict__ mask, int W,
                       int* __restrict__ lenT, int* __restrict__ lenPT,
                       int* __restrict__ offT) {
  const int k = threadIdx.x;   // 0..127
  int l = 0;
  for (int w = 0; w < W; ++w) l += (mask[k * W + w] != 0.f) ? 1 : 0;
  lenT[k]  = l;
  lenPT[k] = (l + 15) & ~15;
  __shared__ int sh[N_BANDS];
  sh[k] = 2 * l;
  __syncthreads();
  for (int s = 1; s < N_BANDS; s <<= 1) {
    int t = (k >= s) ? sh[k - s] : 0;
    __syncthreads();
    sh[k] += t;
    __syncthreads();
  }
  offT[k] = sh[k] - 2 * l;       // exclusive scan of 2*len
  if (k == N_BANDS - 1) offT[N_BANDS] = sh[k];
}

// ============ weight prep (planar K-order for GEMM1 B-fragments) ============
// wB1[band][d][i'], i' = w + c*lenP[band]; value pre_w[band][2w+c][d]
__global__ void prep_w1p(const float* __restrict__ pre_w, const int* __restrict__ lenPT,
                         unsigned short* __restrict__ hh, unsigned short* __restrict__ ll,
                         int i1, int K1PA) {
  int e = blockIdx.x * 256 + threadIdx.x;
  int total = N_BANDS * D_OUTC * K1PA;
  if (e >= total) return;
  int ip = e % K1PA;
  int r  = e / K1PA;
  int d  = r & 127;
  int band = r >> 7;
  int lp = lenPT[band];
  int W  = i1 >> 1;
  float v = 0.f;
  if (ip < 2 * lp) {
    int c = (ip >= lp) ? 1 : 0;
    int w = ip - (c ? lp : 0);
    if (w < W) v = pre_w[((size_t)band * i1 + 2 * w + c) * D_OUTC + d];
  }
  unsigned short h = f2bf(v);
  hh[e] = h;
  ll[e] = f2bf(v - bf2f(h));
}
// wB2[band][o][dd], o in original 2w+c order
__global__ void prep_w2p(const float* __restrict__ post_w,
                         unsigned short* __restrict__ hh, unsigned short* __restrict__ ll,
                         int i1, int OTA) {
  int e = blockIdx.x * 256 + threadIdx.x;
  int total = N_BANDS * OTA * D_OUTC;
  if (e >= total) return;
  int dd = e & 127;
  int r  = e >> 7;
  int o  = r % OTA;
  int band = r / OTA;
  float v = (o < i1) ? post_w[((size_t)band * D_OUTC + dd) * i1 + o] : 0.f;
  unsigned short h = f2bf(v);
  hh[e] = h;
  ll[e] = f2bf(v - bf2f(h));
}

// ============ inverse map: f -> up to 4 y-relative indices (off[k]+2w) ============
__global__ void k_inv(const float* __restrict__ mask, const int* __restrict__ idx,
                      const int* __restrict__ offT, int W,
                      int* __restrict__ inv, int* __restrict__ cnt) {
  int e = blockIdx.x * 256 + threadIdx.x;
  if (e >= N_BANDS * W) return;
  if (mask[e] != 0.f) {
    int k = e / W, w = e - k * W;
    int f = idx[e];
    int slot = atomicAdd(&cnt[f], 1);
    if (slot < 4) inv[f * 4 + slot] = offT[k] + 2 * w;
  }
}

// ============ main: gather + GEMM1 + GEMM2 -> y (no atomics) ============
// block: (32-row m-tile, band). 4 waves: wid&1 = m-half, wid>>1 = N-split half.
__global__ __launch_bounds__(TPB, 4)
void bandsplit_main(const float* __restrict__ x,
                    const unsigned short* __restrict__ wB1h,
                    const unsigned short* __restrict__ wB1l,
                    const unsigned short* __restrict__ wB2h,
                    const unsigned short* __restrict__ wB2l,
                    const float* __restrict__ pre_b,
                    const float* __restrict__ post_b,
                    const float* __restrict__ mel,
                    const float* __restrict__ mask,
                    const int* __restrict__ idx,
                    const int* __restrict__ lenT,
                    const int* __restrict__ lenPT,
                    const int* __restrict__ offT,
                    __half* __restrict__ y,
                    int W, int K1PA)
{
  const int band = blockIdx.y;
  const int lenv = lenT[band];
  if (lenv == 0) return;
  const int lp   = lenPT[band];
  const int k1p  = 2 * lp;              // multiple of 32
  const int nks  = k1p >> 5;
  const int i1e  = 2 * lenv;
  const int nOT  = (i1e + 15) >> 4;     // <= 10
  const int offk = offT[band];

  const int mbase = blockIdx.x * 32;
  const int b  = mbase >> 9;            // T_LEN = 512
  const int t0 = mbase & 511;
  const int tid  = threadIdx.x;
  const int lane = tid & 63;
  const int wid  = tid >> 6;
  const int lr = lane & 15, lk = lane >> 4;
  const int mh = wid & 1;               // m-tile (16 rows)
  const int dh = wid >> 1;              // N-split half

  __shared__ unsigned short smem[2 * 32 * STR1M];   // gAh|gAl, aliased by zAh|zAl
  unsigned short* gAh = smem;
  unsigned short* gAl = smem + 32 * STR1M;
  unsigned short* zAh = smem;
  unsigned short* zAl = smem + 32 * ZSTRM;
  __shared__ float s_melmask[MAX_W];
  __shared__ int   s_idx[MAX_W];
  __shared__ float s_preb[D_OUTC];
  __shared__ float s_postb[2 * MAX_W];

  // ---- stage band tables ----
  for (int j = tid; j < W; j += TPB) {
    float mk = mask[band * W + j];
    s_idx[j]     = idx[band * W + j];
    s_melmask[j] = mel[band * W + j] * mk;
  }
  for (int j = tid; j < D_OUTC; j += TPB) s_preb[j] = pre_b[band * D_OUTC + j];
  for (int j = tid; j < i1e;    j += TPB) s_postb[j] = post_b[band * 2 * W + j];
  __syncthreads();

  // ---- gather (planar i' = w + c*lp): coalesced x reads ----
  const int tot = 32 * k1p;
  for (int e = tid; e < tot; e += TPB) {
    unsigned m = (unsigned)e / (unsigned)k1p;
    int i = e - (int)m * k1p;
    int c = (i >= lp) ? 1 : 0;
    int w = i - (c ? lp : 0);
    float v = 0.f;
    if (w < lenv)
      v = x[((b * C_INC + c) * T_LEN + t0 + (int)m) * F_BINS + s_idx[w]] * s_melmask[w];
    unsigned short h = f2bf(v);
    gAh[m * STR1M + i] = h;
    gAl[m * STR1M + i] = f2bf(v - bf2f(h));
  }
  __syncthreads();

  // ---- GEMM1: z = g . W1  (bf16x3, fp32 accum). wave: m-tile mh, d-tiles dh*4..dh*4+3 ----
  f32x4 acc1[4] = {};
  for (int ks = 0; ks < nks; ++ks) {
    const int arow = (mh * 16 + lr) * STR1M + ks * 32 + lk * 8;
    const short8 ah = *(const short8*)&gAh[arow];
    const short8 al = *(const short8*)&gAl[arow];
    const size_t bbase = ((size_t)band * D_OUTC + dh * 64) * K1PA + ks * 32 + lk * 8;
    #pragma unroll
    for (int t = 0; t < 4; ++t) {
      const short8 bh = *(const short8*)&wB1h[bbase + (size_t)(t * 16 + lr) * K1PA];
      const short8 bl = *(const short8*)&wB1l[bbase + (size_t)(t * 16 + lr) * K1PA];
      acc1[t] = __builtin_amdgcn_mfma_f32_16x16x32_bf16(ah, bh, acc1[t], 0, 0, 0);
      acc1[t] = __builtin_amdgcn_mfma_f32_16x16x32_bf16(al, bh, acc1[t], 0, 0, 0);
      acc1[t] = __builtin_amdgcn_mfma_f32_16x16x32_bf16(ah, bl, acc1[t], 0, 0, 0);
    }
  }
  __syncthreads();   // gA reads complete before zA overwrite

  // ---- z + bias -> LDS (hi/lo), C-layout: col=lr, row=lk*4+r ----
  #pragma unroll
  for (int t = 0; t < 4; ++t) {
    const int d = (dh * 4 + t) * 16 + lr;
    const float pb = s_preb[d];
    #pragma unroll
    for (int r = 0; r < 4; ++r) {
      const int m = mh * 16 + lk * 4 + r;
      float z = acc1[t][r] + pb;
      unsigned short h = f2bf(z);
      zAh[m * ZSTRM + d] = h;
      zAl[m * ZSTRM + d] = f2bf(z - bf2f(h));
    }
  }
  __syncthreads();

  // ---- GEMM2: y = z . W2. wave: m-tile mh, o-tiles ot = dh, dh+2, ... ----
  f32x4 acc2[5] = {};
  #pragma unroll
  for (int ks = 0; ks < 4; ++ks) {
    const int arow = (mh * 16 + lr) * ZSTRM + ks * 32 + lk * 8;
    const short8 ah = *(const short8*)&zAh[arow];
    const short8 al = *(const short8*)&zAl[arow];
    #pragma unroll
    for (int t = 0; t < 5; ++t) {
      const int ot = dh + 2 * t;
      if (ot < nOT) {
        const size_t bo = ((size_t)band * K1PA + ot * 16 + lr) * D_OUTC + ks * 32 + lk * 8;
        const short8 bh = *(const short8*)&wB2h[bo];
        const short8 bl = *(const short8*)&wB2l[bo];
        acc2[t] = __builtin_amdgcn_mfma_f32_16x16x32_bf16(ah, bh, acc2[t], 0, 0, 0);
        acc2[t] = __builtin_amdgcn_mfma_f32_16x16x32_bf16(al, bh, acc2[t], 0, 0, 0);
        acc2[t] = __builtin_amdgcn_mfma_f32_16x16x32_bf16(ah, bl, acc2[t], 0, 0, 0);
      }
    }
  }

  // ---- epilogue: +bias, store y (coalesced fp16, no mask/ola here) ----
  #pragma unroll
  for (int t = 0; t < 5; ++t) {
    const int ot = dh + 2 * t;
    if (ot < nOT) {
      const int o = ot * 16 + lr;
      if (o < i1e) {
        const float pb = s_postb[o];
        #pragma unroll
        for (int r = 0; r < 4; ++r) {
          const int m = mh * 16 + lk * 4 + r;
          y[(size_t)(b * T_LEN + t0 + m) * SCAP + offk + o] = __float2half_rn(acc2[t][r] + pb);
        }
      }
    }
  }
}

// ============ merge: out[b,c,t,f] = (sum of <=2 y contributions) / ola[f] ============
__global__ __launch_bounds__(256, 8)
void k_merge(const __half* __restrict__ y, const int* __restrict__ inv,
             const float* __restrict__ ola, float* __restrict__ out, int total) {
  for (int e = blockIdx.x * 256 + threadIdx.x; e < total; e += gridDim.x * 256) {
    int f  = e % F_BINS;
    int r  = e / F_BINS;          // (b*2+c)*512 + t
    int t  = r & 511;
    int bc = r >> 9;
    int c  = bc & 1;
    int b  = bc >> 1;
    const int4 iv = *reinterpret_cast<const int4*>(&inv[f * 4]);
    const size_t base = (size_t)(b * T_LEN + t) * SCAP + c;
    float s = 0.f;
    if (iv.x >= 0) s += __half2float(y[base + iv.x]);
    if (iv.y >= 0) s += __half2float(y[base + iv.y]);
    if (iv.z >= 0) s += __half2float(y[base + iv.z]);
    if (iv.w >= 0) s += __half2float(y[base + iv.w]);
    out[e] = s / ola[f];
  }
}

// ================= fallback 1: R2 mfma path (proven, atomics) =================
constexpr int MAX_K1P  = 160;
constexpr int STR1_MAX = MAX_K1P + 8;
constexpr int ZSTR     = 136;

__global__ void prep_w1_r2(const float* __restrict__ pre_w,
                           unsigned short* __restrict__ hh, unsigned short* __restrict__ ll,
                           int i1, int K1P) {
  int e = blockIdx.x * 256 + threadIdx.x;
  int total = N_BANDS * 128 * K1P;
  if (e >= total) return;
  int kk = e % K1P;
  int rem = e / K1P;
  int d = rem & 127;
  int band = rem >> 7;
  float v = (kk < i1) ? pre_w[((size_t)band * i1 + kk) * 128 + d] : 0.f;
  unsigned short h = f2bf(v);
  hh[e] = h;
  ll[e] = f2bf(v - bf2f(h));
}
__global__ void prep_w2_r2(const float* __restrict__ post_w,
                           unsigned short* __restrict__ hh, unsigned short* __restrict__ ll,
                           int i1, int OSTR) {
  int e = blockIdx.x * 256 + threadIdx.x;
  int total = N_BANDS * OSTR * 128;
  if (e >= total) return;
  int dd = e & 127;
  int rem = e >> 7;
  int o = rem % OSTR;
  int band = rem / OSTR;
  float v = (o < i1) ? post_w[((size_t)band * 128 + dd) * i1 + o] : 0.f;
  unsigned short h = f2bf(v);
  hh[e] = h;
  ll[e] = f2bf(v - bf2f(h));
}

__global__ __launch_bounds__(TPB, 3)
void bandsplit_mfma(const float* __restrict__ x,
                    const unsigned short* __restrict__ wB1h,
                    const unsigned short* __restrict__ wB1l,
                    const unsigned short* __restrict__ wB2h,
                    const unsigned short* __restrict__ wB2l,
                    const float* __restrict__ pre_b,
                    const float* __restrict__ post_b,
                    const float* __restrict__ mel,
                    const float* __restrict__ mask,
                    const float* __restrict__ ola,
                    const int* __restrict__ idx,
                    float* __restrict__ out,
                    int W, int i1, int K1P)
{
  const int k     = blockIdx.y;
  const int mbase = blockIdx.x * 64;
  const int b     = mbase >> 9;
  const int t0    = mbase & 511;
  const int tid   = threadIdx.x;
  const int lane  = tid & 63;
  const int wid   = tid >> 6;
  const int lr    = lane & 15;
  const int lk    = lane >> 4;
  const int STR1  = K1P + 8;

  __shared__ unsigned short smem[64 * STR1_MAX * 2];
  unsigned short* gAh = smem;
  unsigned short* gAl = smem + 64 * STR1;
  unsigned short* zAh = smem;
  unsigned short* zAl = smem + 64 * ZSTR;
  __shared__ float s_melmask[MAX_W], s_mask_s[MAX_W], s_iola[MAX_W];
  __shared__ int   s_idx[MAX_W];
  __shared__ float s_preb[128];
  __shared__ float s_postb[2 * MAX_W];

  for (int j = tid; j < W; j += TPB) {
    int   f  = idx[k * W + j];
    float mv = mel[k * W + j];
    float mk = mask[k * W + j];
    s_idx[j]     = f;
    s_melmask[j] = mv * mk;
    s_mask_s[j]  = mk;
    s_iola[j]    = 1.0f / ola[f];
  }
  for (int j = tid; j < 128; j += TPB) s_preb[j]  = pre_b[k * 128 + j];
  for (int j = tid; j < i1;  j += TPB) s_postb[j] = post_b[k * i1 + j];
  __syncthreads();

  int len = 0;
  for (int w = 0; w < W; ++w) len += (s_mask_s[w] != 0.f) ? 1 : 0;
  const int i1e  = 2 * len;
  const int k1p  = (i1e + 31) & ~31;
  const int nks1 = k1p >> 5;
  const int nOT  = (i1e + 15) >> 4;

  {
    int m = tid / k1p;
    int i = tid - m * k1p;
    while (m < 64) {
      int w = i >> 1, c = i & 1;
      float v = 0.f;
      if (w < W) {
        float mm = s_melmask[w];
        if (mm != 0.f)
          v = x[((b * C_INC + c) * T_LEN + t0 + m) * F_BINS + s_idx[w]] * mm;
      }
      unsigned short h = f2bf(v);
      gAh[m * STR1 + i] = h;
      gAl[m * STR1 + i] = f2bf(v - bf2f(h));
      i += TPB;
      while (i >= k1p) { i -= k1p; ++m; }
    }
  }
  __syncthreads();

  f32x4 acc1[8] = {};
  const int m0 = wid * 16;
  for (int ks = 0; ks < nks1; ++ks) {
    const short8 ah = *(const short8*)&gAh[(m0 + lr) * STR1 + ks * 32 + lk * 8];
    const short8 al = *(const short8*)&gAl[(m0 + lr) * STR1 + ks * 32 + lk * 8];
    #pragma unroll
    for (int dt = 0; dt < 8; ++dt) {
      const int off = (k * 128 + dt * 16 + lr) * K1P + ks * 32 + lk * 8;
      const short8 bh = *(const short8*)&wB1h[off];
      const short8 bl = *(const short8*)&wB1l[off];
      acc1[dt] = __builtin_amdgcn_mfma_f32_16x16x32_bf16(ah, bh, acc1[dt], 0, 0, 0);
      acc1[dt] = __builtin_amdgcn_mfma_f32_16x16x32_bf16(al, bh, acc1[dt], 0, 0, 0);
      acc1[dt] = __builtin_amdgcn_mfma_f32_16x16x32_bf16(ah, bl, acc1[dt], 0, 0, 0);
    }
  }
  __syncthreads();

  #pragma unroll
  for (int dt = 0; dt < 8; ++dt) {
    const int d = dt * 16 + lr;
    #pragma unroll
    for (int r = 0; r < 4; ++r) {
      const int m = m0 + lk * 4 + r;
      float z = acc1[dt][r] + s_preb[d];
      unsigned short h = f2bf(z);
      zAh[m * ZSTR + d] = h;
      zAl[m * ZSTR + d] = f2bf(z - bf2f(h));
    }
  }
  __syncthreads();

  f32x4 acc2[10] = {};
  for (int ks = 0; ks < 4; ++ks) {
    const short8 ah = *(const short8*)&zAh[(m0 + lr) * ZSTR + ks * 32 + lk * 8];
    const short8 al = *(const short8*)&zAl[(m0 + lr) * ZSTR + ks * 32 + lk * 8];
    #pragma unroll
    for (int ot = 0; ot < 10; ++ot) {
      if (ot < nOT) {
        const int off = (k * K1P + ot * 16 + lr) * 128 + ks * 32 + lk * 8;
        const short8 bh = *(const short8*)&wB2h[off];
        const short8 bl = *(const short8*)&wB2l[off];
        acc2[ot] = __builtin_amdgcn_mfma_f32_16x16x32_bf16(ah, bh, acc2[ot], 0, 0, 0);
        acc2[ot] = __builtin_amdgcn_mfma_f32_16x16x32_bf16(al, bh, acc2[ot], 0, 0, 0);
        acc2[ot] = __builtin_amdgcn_mfma_f32_16x16x32_bf16(ah, bl, acc2[ot], 0, 0, 0);
      }
    }
  }

  #pragma unroll
  for (int ot = 0; ot < 10; ++ot) {
    if (ot < nOT) {
      const int o = ot * 16 + lr;
      if (o < i1e) {
        const int w = o >> 1, c = o & 1;
        const float sc = s_iola[w];
        const float bb = s_postb[o];
        const int   f  = s_idx[w];
        #pragma unroll
        for (int r = 0; r < 4; ++r) {
          const int m = m0 + lk * 4 + r;
          atomicAdd(&out[((b * C_INC + c) * T_LEN + t0 + m) * F_BINS + f],
                    (acc2[ot][r] + bb) * sc);
        }
      }
    }
  }
}

// ================= fallback 2: naive (any W) =================
__global__ void bandsplit_naive(const float* __restrict__ x,
                                const float* __restrict__ pre_w,
                                const float* __restrict__ pre_b,
                                const float* __restrict__ post_w,
                                const float* __restrict__ post_b,
                                const float* __restrict__ mel,
                                const float* __restrict__ mask,
                                const float* __restrict__ ola,
                                const int*   __restrict__ idx,
                                float* __restrict__ out,
                                int W)
{
    const int i1 = 2 * W;
    extern __shared__ float sh[];
    float* g = sh;
    float* z = sh + i1;
    const int m = blockIdx.x, k = blockIdx.y;
    const int b = m / T_LEN, t = m % T_LEN;
    const int tid = threadIdx.x;
    for (int j = tid; j < i1; j += 128) {
        int w = j >> 1, c = j & 1;
        int f = idx[k * W + w];
        g[j] = x[((b * C_INC + c) * T_LEN + t) * F_BINS + f] * mel[k * W + w] * mask[k * W + w];
    }
    __syncthreads();
    {
        int d = tid;
        float a = pre_b[k * D_OUTC + d];
        for (int i = 0; i < i1; ++i) a += g[i] * pre_w[(k * i1 + i) * D_OUTC + d];
        z[d] = a;
    }
    __syncthreads();
    for (int o = tid; o < i1; o += 128) {
        int w = o >> 1, c = o & 1;
        float mk = mask[k * W + w];
        if (mk == 0.f) continue;
        float a = post_b[k * i1 + o];
        for (int d = 0; d < D_OUTC; ++d) a += z[d] * post_w[(k * D_OUTC + d) * i1 + o];
        int f = idx[k * W + w];
        atomicAdd(&out[((b * C_INC + c) * T_LEN + t) * F_BINS + f], a * mk / ola[f]);
    }
}

extern "C" void kernel_launch(void* const* d_in, const int* in_sizes, int n_in,
                              void* d_out, int out_size, void* d_ws, size_t ws_size,
                              hipStream_t stream) {
    const float* x      = (const float*)d_in[0];
    const float* pre_w  = (const float*)d_in[1];
    const float* pre_b  = (const float*)d_in[2];
    const float* post_w = (const float*)d_in[3];
    const float* post_b = (const float*)d_in[4];
    const float* mel    = (const float*)d_in[5];
    const float* mask   = (const float*)d_in[6];
    const float* ola    = (const float*)d_in[7];
    const int*   idxp   = (const int*)d_in[8];
    float* out = (float*)d_out;

    const int W  = in_sizes[8] / N_BANDS;
    const int i1 = 2 * W;
    const int Mrows = in_sizes[0] / (C_INC * F_BINS);   // B*T
    const int K1PA = 2 * ((W + 15) & ~15);              // planar K alloc, <=160 for W<=80

    // ---- workspace layout for fast path ----
    const size_t S1 = (size_t)N_BANDS * D_OUTC * K1PA;          // elems per split-weight array
    const size_t wbytes   = 8 * S1;                             // 4 arrays x 2B
    const size_t inv_off  = (wbytes + 15) & ~(size_t)15;        // int inv[F_BINS*4] (16B aligned)
    const size_t cnt_off  = inv_off + (size_t)F_BINS * 4 * 4;   // int cnt[F_BINS]
    const size_t len_off  = cnt_off + (size_t)F_BINS * 4;       // int lenT[128]
    const size_t lenp_off = len_off + N_BANDS * 4;              // int lenPT[128]
    const size_t offt_off = lenp_off + N_BANDS * 4;             // int offT[129]
    const size_t y_off    = (offt_off + (N_BANDS + 1) * 4 + 255) & ~(size_t)255;
    const size_t need     = y_off + (size_t)Mrows * SCAP * sizeof(__half);

    if (W <= MAX_W && (Mrows % T_LEN) == 0 && ws_size >= need) {
        char* ws = (char*)d_ws;
        unsigned short* wB1h = (unsigned short*)ws;
        unsigned short* wB1l = wB1h + S1;
        unsigned short* wB2h = wB1l + S1;
        unsigned short* wB2l = wB2h + S1;
        int* inv  = (int*)(ws + inv_off);
        int* cnt  = (int*)(ws + cnt_off);
        int* lenT = (int*)(ws + len_off);
        int* lenPT= (int*)(ws + lenp_off);
        int* offT = (int*)(ws + offt_off);
        __half* y = (__half*)(ws + y_off);

        hipMemsetAsync(cnt, 0,    (size_t)F_BINS * 4, stream);
        hipMemsetAsync(inv, 0xFF, (size_t)F_BINS * 4 * 4, stream);
        k_meta<<<1, N_BANDS, 0, stream>>>(mask, W, lenT, lenPT, offT);
        const int nb = (int)((S1 + 255) / 256);
        prep_w1p<<<nb, 256, 0, stream>>>(pre_w, lenPT, wB1h, wB1l, i1, K1PA);
        prep_w2p<<<nb, 256, 0, stream>>>(post_w, wB2h, wB2l, i1, K1PA);
        k_inv<<<(N_BANDS * W + 255) / 256, 256, 0, stream>>>(mask, idxp, offT, W, inv, cnt);
        dim3 grid(Mrows / 32, N_BANDS);
        bandsplit_main<<<grid, TPB, 0, stream>>>(x, wB1h, wB1l, wB2h, wB2l,
                                                 pre_b, post_b, mel, mask, idxp,
                                                 lenT, lenPT, offT, y, W, K1PA);
        k_merge<<<2048, 256, 0, stream>>>(y, inv, ola, out, out_size);
        return;
    }

    // ---- fallback: R2 proven path (atomics; needs 21 MB ws) ----
    hipMemsetAsync(d_out, 0, (size_t)out_size * sizeof(float), stream);
    const int K1P = (i1 + 31) & ~31;
    const size_t S1b = (size_t)N_BANDS * 128 * K1P;
    const size_t needb = S1b * 4 * sizeof(unsigned short);
    if (W <= MAX_W && (Mrows % 64) == 0 && ws_size >= needb) {
        unsigned short* wB1h = (unsigned short*)d_ws;
        unsigned short* wB1l = wB1h + S1b;
        unsigned short* wB2h = wB1l + S1b;
        unsigned short* wB2l = wB2h + S1b;
        const int nb = (int)((S1b + 255) / 256);
        prep_w1_r2<<<nb, 256, 0, stream>>>(pre_w,  wB1h, wB1l, i1, K1P);
        prep_w2_r2<<<nb, 256, 0, stream>>>(post_w, wB2h, wB2l, i1, K1P);
        dim3 grid(Mrows / 64, N_BANDS);
        bandsplit_mfma<<<grid, TPB, 0, stream>>>(x, wB1h, wB1l, wB2h, wB2l,
                                                 pre_b, post_b, mel, mask, ola, idxp,
                                                 out, W, i1, K1P);
    } else {
        dim3 grid(Mrows, N_BANDS);
        size_t shmem = (size_t)(2 * W + D_OUTC) * sizeof(float);
        bandsplit_naive<<<grid, 128, shmem, stream>>>(x, pre_w, pre_b, post_w, post_b,
                                                      mel, mask, ola, idxp, out, W);
    }
}